// Round 3
// baseline (3932.170 us; speedup 1.0000x reference)
//
#include <hip/hip_runtime.h>
#include <hip/hip_bf16.h>

typedef __hip_bfloat16 bf16;

#define IN_CH 32
#define HID 128
#define OUT_CH 32

// ---------- dtype-agnostic loaders (flags are wave-uniform) ----------
__device__ __forceinline__ float ldf(const void* __restrict__ p, size_t idx, int isbf16) {
    return isbf16 ? __bfloat162float(((const bf16*)p)[idx])
                  : ((const float*)p)[idx];
}
__device__ __forceinline__ int ld_edge(const int* __restrict__ ei, size_t elem, int wide) {
    return wide ? ei[2 * elem] : ei[elem];   // int64: little-endian low word
}

// ---------- sniff dtypes: flags[0]=float_is_bf16, flags[1]=edge_is_i64 ----------
__global__ void k_detect(const unsigned short* __restrict__ xraw,
                         const int* __restrict__ ei, int* __restrict__ flags) {
    __shared__ int cnt_exp, any_nz;
    if (threadIdx.x == 0) { cnt_exp = 0; any_nz = 0; }
    __syncthreads();
    int local = 0;
    for (int k = threadIdx.x; k < 4096; k += 256) {
        int e = (xraw[k] >> 7) & 0xFF;
        if (e >= 100 && e <= 140) ++local;
    }
    atomicAdd(&cnt_exp, local);
    for (int k = threadIdx.x; k < 2048; k += 256)
        if (ei[2 * k + 1] != 0) any_nz = 1;   // benign race
    __syncthreads();
    if (threadIdx.x == 0) {
        flags[0] = (cnt_exp > 3500) ? 1 : 0;  // bf16 vs f32
        flags[1] = any_nz ? 0 : 1;            // i32 vs i64
    }
}

__global__ void k_count(const int* __restrict__ ei, int n_edges,
                        const int* __restrict__ flags, int* __restrict__ deg) {
    int e = blockIdx.x * blockDim.x + threadIdx.x;
    if (e >= n_edges) return;
    int w = flags[1];
    atomicAdd(&deg[ld_edge(ei, (size_t)n_edges + e, w)], 1);
}

// single-block exclusive scan: deg[0..N-1] -> offsets in place, deg[N]=E, cursor=copy
__global__ __launch_bounds__(1024) void k_scan(int* __restrict__ deg, int* __restrict__ cursor,
                                               int n_nodes) {
    __shared__ int part[1024];
    const int C = (n_nodes + 1023) / 1024;
    int t = threadIdx.x;
    int b = t * C;
    int e = min(b + C, n_nodes);
    int s = 0;
    for (int k = b; k < e; ++k) s += deg[k];
    part[t] = s;
    __syncthreads();
    if (t == 0) {
        int r = 0;
        for (int j = 0; j < 1024; ++j) { int v = part[j]; part[j] = r; r += v; }
        deg[n_nodes] = r;
    }
    __syncthreads();
    int run = part[t];
    for (int k = b; k < e; ++k) {
        int v = deg[k];
        deg[k] = run;
        cursor[k] = run;
        run += v;
    }
}

__global__ void k_fill(const int* __restrict__ ei, int n_edges,
                       const int* __restrict__ flags,
                       int* __restrict__ cursor, int* __restrict__ csr) {
    int e = blockIdx.x * blockDim.x + threadIdx.x;
    if (e >= n_edges) return;
    int w = flags[1];
    int d = ld_edge(ei, (size_t)n_edges + e, w);
    int s = ld_edge(ei, (size_t)e, w);
    int p = atomicAdd(&cursor[d], 1);
    csr[p] = s;
}

// ---- layer 1: h[i] = relu(mean_j x[j] @ W1l^T + x[i] @ W1r^T + b1), 32 -> 128 ----
__global__ __launch_bounds__(128) void k_l1(
        const void* __restrict__ x,
        const int* __restrict__ off, const int* __restrict__ csr,
        const void* __restrict__ W1l, const void* __restrict__ W1r,
        const void* __restrict__ b1,
        const int* __restrict__ flags,
        bf16* __restrict__ h, int n_nodes) {
    __shared__ float red[4][IN_CH];
    __shared__ float mean_s[IN_CH];
    __shared__ float xr[IN_CH];
    int i = blockIdx.x;
    if (i >= n_nodes) return;
    int fb = flags[0];
    int t = threadIdx.x;
    int c = t & 31, s = t >> 5;
    int beg = off[i], end = off[i + 1];
    float acc = 0.0f;
    for (int k = beg + s; k < end; k += 4) {
        int src = csr[k];
        acc += ldf(x, (size_t)src * IN_CH + c, fb);
    }
    red[s][c] = acc;
    __syncthreads();
    if (s == 0) {
        float d = (float)(end - beg);
        if (d < 1.0f) d = 1.0f;
        mean_s[c] = (red[0][c] + red[1][c] + red[2][c] + red[3][c]) / d;
        xr[c] = ldf(x, (size_t)i * IN_CH + c, fb);
    }
    __syncthreads();
    int o = t;  // 0..127
    float a = ldf(b1, o, fb);
#pragma unroll
    for (int c2 = 0; c2 < IN_CH; ++c2)
        a += mean_s[c2] * ldf(W1l, o * IN_CH + c2, fb)
           + xr[c2]     * ldf(W1r, o * IN_CH + c2, fb);
    h[(size_t)i * HID + o] = __float2bfloat16(a > 0.0f ? a : 0.0f);
}

// ---- layer 2: out[i] = mean_j h[j] @ W2l^T + h[i] @ W2r^T + b2, 128 -> 32 ----
__global__ __launch_bounds__(128) void k_l2(
        const bf16* __restrict__ h,
        const int* __restrict__ off, const int* __restrict__ csr,
        const void* __restrict__ W2l, const void* __restrict__ W2r,
        const void* __restrict__ b2,
        const int* __restrict__ flags,
        void* __restrict__ out, int n_nodes) {
    __shared__ float mean_s[HID];
    __shared__ float hr[HID];
    __shared__ float red[4][OUT_CH];
    int i = blockIdx.x;
    if (i >= n_nodes) return;
    int fb = flags[0];
    int t = threadIdx.x;  // channel 0..127
    int beg = off[i], end = off[i + 1];
    float acc = 0.0f;
    for (int k = beg; k < end; ++k) {
        int src = csr[k];
        acc += __bfloat162float(h[(size_t)src * HID + t]);
    }
    float d = (float)(end - beg);
    if (d < 1.0f) d = 1.0f;
    mean_s[t] = acc / d;
    hr[t] = __bfloat162float(h[(size_t)i * HID + t]);
    __syncthreads();
    int o = t & 31, s = t >> 5;
    float a = 0.0f;
#pragma unroll
    for (int j = 0; j < 32; ++j) {
        int c = s * 32 + j;
        a += mean_s[c] * ldf(W2l, o * HID + c, fb)
           + hr[c]     * ldf(W2r, o * HID + c, fb);
    }
    red[s][o] = a;
    __syncthreads();
    if (s == 0) {
        float v = red[0][o] + red[1][o] + red[2][o] + red[3][o] + ldf(b2, o, fb);
        size_t oi = (size_t)i * OUT_CH + o;
        if (fb) ((bf16*)out)[oi] = __float2bfloat16(v);
        else    ((float*)out)[oi] = v;
    }
}

extern "C" void kernel_launch(void* const* d_in, const int* in_sizes, int n_in,
                              void* d_out, int out_size, void* d_ws, size_t ws_size,
                              hipStream_t stream) {
    const void* x   = d_in[0];
    const int*  ei  = (const int*)d_in[1];
    const void* W1l = d_in[2];
    const void* W1r = d_in[3];
    const void* b1  = d_in[4];
    const void* W2l = d_in[5];
    const void* W2r = d_in[6];
    const void* b2  = d_in[7];

    int n_nodes = in_sizes[0] / IN_CH;
    int n_edges = in_sizes[1] / 2;

    // ws layout (bytes), total ~33 MB:
    //   [0,256)            flags (2 ints)
    //   [256, ...)         deg -> offsets in place ((N+1) ints)
    //   next (128-aligned) cursor (N ints)
    //   next               csr_src (E ints)
    //   next (256-aligned) h (N*HID bf16)
    char* ws = (char*)d_ws;
    size_t o_off = 256;
    size_t o_cur = (o_off + (size_t)(n_nodes + 1) * 4 + 127) & ~(size_t)127;
    size_t o_csr = (o_cur + (size_t)n_nodes * 4 + 127) & ~(size_t)127;
    size_t o_h   = (o_csr + (size_t)n_edges * 4 + 255) & ~(size_t)255;

    int*  flags  = (int*)ws;
    int*  deg    = (int*)(ws + o_off);   // becomes offsets after k_scan
    int*  cursor = (int*)(ws + o_cur);
    int*  csr    = (int*)(ws + o_csr);
    bf16* h      = (bf16*)(ws + o_h);

    hipMemsetAsync(deg, 0, (size_t)(n_nodes + 1) * 4, stream);

    k_detect<<<1, 256, 0, stream>>>((const unsigned short*)x, ei, flags);
    k_count<<<(n_edges + 255) / 256, 256, 0, stream>>>(ei, n_edges, flags, deg);
    k_scan<<<1, 1024, 0, stream>>>(deg, cursor, n_nodes);
    k_fill<<<(n_edges + 255) / 256, 256, 0, stream>>>(ei, n_edges, flags, cursor, csr);

    k_l1<<<n_nodes, 128, 0, stream>>>(x, deg, csr, W1l, W1r, b1, flags, h, n_nodes);
    k_l2<<<n_nodes, 128, 0, stream>>>(h, deg, csr, W2l, W2r, b2, flags, d_out, n_nodes);
}

// Round 4
// 786.381 us; speedup vs baseline: 5.0003x; 5.0003x over previous
//
#include <hip/hip_runtime.h>
#include <hip/hip_bf16.h>

typedef __hip_bfloat16 bf16;
typedef unsigned short ush;
typedef __attribute__((ext_vector_type(8))) unsigned short ush8;
typedef __attribute__((ext_vector_type(4))) float f4;

#define IN_CH 32
#define HID 128
#define OUT_CH 32

__device__ __forceinline__ float bf2f(ush u) {
    return __uint_as_float(((unsigned)u) << 16);
}
__device__ __forceinline__ ush f2bf(float f) {
    __hip_bfloat16 b = __float2bfloat16(f);
    return __builtin_bit_cast(ush, b);
}
__device__ __forceinline__ float ldf(const void* __restrict__ p, size_t idx, int isbf16) {
    return isbf16 ? bf2f(((const ush*)p)[idx]) : ((const float*)p)[idx];
}
__device__ __forceinline__ int ld_edge(const int* __restrict__ ei, size_t elem, int wide) {
    return wide ? ei[2 * elem] : ei[elem];
}

// ---------- sniff dtypes: flags[0]=float_is_bf16, flags[1]=edge_is_i64 ----------
__global__ void k_detect(const unsigned short* __restrict__ xraw,
                         const int* __restrict__ ei, int* __restrict__ flags) {
    __shared__ int cnt_exp, any_nz;
    if (threadIdx.x == 0) { cnt_exp = 0; any_nz = 0; }
    __syncthreads();
    int local = 0;
    for (int k = threadIdx.x; k < 4096; k += 256) {
        int e = (xraw[k] >> 7) & 0xFF;
        if (e >= 100 && e <= 140) ++local;
    }
    atomicAdd(&cnt_exp, local);
    for (int k = threadIdx.x; k < 2048; k += 256)
        if (ei[2 * k + 1] != 0) any_nz = 1;   // benign race
    __syncthreads();
    if (threadIdx.x == 0) {
        flags[0] = (cnt_exp > 3500) ? 1 : 0;
        flags[1] = any_nz ? 0 : 1;
    }
}

__global__ void k_count(const int* __restrict__ ei, int n_edges,
                        const int* __restrict__ flags, int* __restrict__ deg) {
    int e = blockIdx.x * blockDim.x + threadIdx.x;
    if (e >= n_edges) return;
    int w = flags[1];
    atomicAdd(&deg[ld_edge(ei, (size_t)n_edges + e, w)], 1);
}

__global__ __launch_bounds__(1024) void k_scan(int* __restrict__ deg, int* __restrict__ cursor,
                                               int n_nodes) {
    __shared__ int part[1024];
    const int C = (n_nodes + 1023) / 1024;
    int t = threadIdx.x;
    int b = t * C;
    int e = min(b + C, n_nodes);
    int s = 0;
    for (int k = b; k < e; ++k) s += deg[k];
    part[t] = s;
    __syncthreads();
    if (t == 0) {
        int r = 0;
        for (int j = 0; j < 1024; ++j) { int v = part[j]; part[j] = r; r += v; }
        deg[n_nodes] = r;
    }
    __syncthreads();
    int run = part[t];
    for (int k = b; k < e; ++k) {
        int v = deg[k];
        deg[k] = run;
        cursor[k] = run;
        run += v;
    }
}

__global__ void k_fill(const int* __restrict__ ei, int n_edges,
                       const int* __restrict__ flags,
                       int* __restrict__ cursor, int* __restrict__ csr) {
    int e = blockIdx.x * blockDim.x + threadIdx.x;
    if (e >= n_edges) return;
    int w = flags[1];
    int d = ld_edge(ei, (size_t)n_edges + e, w);
    int s = ld_edge(ei, (size_t)e, w);
    int p = atomicAdd(&cursor[d], 1);
    csr[p] = s;
}

// ==== layer 1: h[i] = relu(mean_j x[j] @ W1l^T + x[i] @ W1r^T + b1), 32 -> 128 ====
// wave-per-node; lane = (slot 0..15 = edge slot, chunk 0..3 = 8-channel chunk)
__global__ __launch_bounds__(256) void k_l1(
        const void* __restrict__ x,
        const int* __restrict__ off, const int* __restrict__ csr,
        const void* __restrict__ W1l, const void* __restrict__ W1r,
        const void* __restrict__ b1,
        const int* __restrict__ flags,
        ush* __restrict__ hout, int n_nodes, int n_edges) {
    __shared__ ush wst[2 * HID * IN_CH];   // 16 KB: W1l then W1r, bf16 [o][c]
    int fb = flags[0];
    int t = threadIdx.x;
    for (int idx = t; idx < HID * IN_CH; idx += 256) {
        wst[idx]                 = f2bf(ldf(W1l, idx, fb));
        wst[HID * IN_CH + idx]   = f2bf(ldf(W1r, idx, fb));
    }
    __syncthreads();
    int wave = t >> 6, lane = t & 63;
    int slot = lane >> 2;    // 0..15
    int chunk = lane & 3;    // 0..3
    // register-stationary weights: outputs o = slot*8+j (128), channels chunk*8..+7 (32)
    ush8 wlr[8], wrr[8];
    float bsr[8];
#pragma unroll
    for (int j = 0; j < 8; ++j) {
        int o = slot * 8 + j;
        wlr[j] = *(const ush8*)&wst[o * IN_CH + chunk * 8];
        wrr[j] = *(const ush8*)&wst[HID * IN_CH + o * IN_CH + chunk * 8];
        bsr[j] = ldf(b1, o, fb);
    }
    int gw = blockIdx.x * 4 + wave;
    int nw = gridDim.x * 4;
    for (int i = gw; i < n_nodes; i += nw) {
        int beg = off[i], end = off[i + 1];
        float acc[8] = {0, 0, 0, 0, 0, 0, 0, 0};
        if (fb) {
            const ush* xb = (const ush*)x;
            for (int base = beg; base < end; base += 64) {
                int idxv = csr[min(base + lane, n_edges - 1)];
                int lim = min(64, end - base);
                for (int g = 0; g < lim; g += 16) {
                    int k = g + slot;
                    int src = __shfl(idxv, k);
                    bool ok = k < lim;
                    ush8 v = *(const ush8*)(xb + (size_t)(ok ? src : i) * IN_CH + chunk * 8);
#pragma unroll
                    for (int j = 0; j < 8; ++j) acc[j] += ok ? bf2f(v[j]) : 0.0f;
                }
            }
        } else {
            const float* xb = (const float*)x;
            for (int base = beg; base < end; base += 64) {
                int idxv = csr[min(base + lane, n_edges - 1)];
                int lim = min(64, end - base);
                for (int g = 0; g < lim; g += 16) {
                    int k = g + slot;
                    int src = __shfl(idxv, k);
                    bool ok = k < lim;
                    const float* rp = xb + (size_t)(ok ? src : i) * IN_CH + chunk * 8;
                    f4 a0 = *(const f4*)rp;
                    f4 a1 = *(const f4*)(rp + 4);
#pragma unroll
                    for (int j = 0; j < 4; ++j) {
                        acc[j]     += ok ? a0[j] : 0.0f;
                        acc[4 + j] += ok ? a1[j] : 0.0f;
                    }
                }
            }
        }
        // reduce over slot bits (lane bits 2..5)
#pragma unroll
        for (int j = 0; j < 8; ++j) {
            acc[j] += __shfl_xor(acc[j], 4);
            acc[j] += __shfl_xor(acc[j], 8);
            acc[j] += __shfl_xor(acc[j], 16);
            acc[j] += __shfl_xor(acc[j], 32);
        }
        int deg = end - beg;
        float rdeg = 1.0f / (float)(deg > 1 ? deg : 1);
        float mean[8], sv[8];
        if (fb) {
            ush8 svv = *(const ush8*)((const ush*)x + (size_t)i * IN_CH + chunk * 8);
#pragma unroll
            for (int j = 0; j < 8; ++j) sv[j] = bf2f(svv[j]);
        } else {
            const float* rp = (const float*)x + (size_t)i * IN_CH + chunk * 8;
            f4 a0 = *(const f4*)rp;
            f4 a1 = *(const f4*)(rp + 4);
#pragma unroll
            for (int j = 0; j < 4; ++j) { sv[j] = a0[j]; sv[4 + j] = a1[j]; }
        }
#pragma unroll
        for (int j = 0; j < 8; ++j) mean[j] = acc[j] * rdeg;
        // per-lane partial GEMV: 8 outputs x 8 channels
        float po[8];
#pragma unroll
        for (int j = 0; j < 8; ++j) {
            float s = 0.0f;
#pragma unroll
            for (int c = 0; c < 8; ++c)
                s += mean[c] * bf2f(wlr[j][c]) + sv[c] * bf2f(wrr[j][c]);
            po[j] = s;
        }
        // reduce over chunk bits (lane bits 0,1)
#pragma unroll
        for (int j = 0; j < 8; ++j) {
            po[j] += __shfl_xor(po[j], 1);
            po[j] += __shfl_xor(po[j], 2);
        }
        if (chunk == 0) {
            ush8 ov;
#pragma unroll
            for (int j = 0; j < 8; ++j) {
                float v = po[j] + bsr[j];
                ov[j] = f2bf(v > 0.0f ? v : 0.0f);
            }
            *(ush8*)(hout + (size_t)i * HID + slot * 8) = ov;
        }
    }
}

// ==== layer 2: out[i] = mean_j h[j] @ W2l^T + h[i] @ W2r^T + b2, 128 -> 32 ====
// wave-per-node; lane = (slot 0..3 = edge slot, chunk 0..15 = 8-channel chunk)
__global__ __launch_bounds__(256) void k_l2(
        const ush* __restrict__ h,
        const int* __restrict__ off, const int* __restrict__ csr,
        const void* __restrict__ W2l, const void* __restrict__ W2r,
        const void* __restrict__ b2,
        const int* __restrict__ flags,
        void* __restrict__ out, int n_nodes, int n_edges) {
    __shared__ ush wst[2 * OUT_CH * HID];  // 16 KB
    int fb = flags[0];
    int t = threadIdx.x;
    for (int idx = t; idx < OUT_CH * HID; idx += 256) {
        wst[idx]                  = f2bf(ldf(W2l, idx, fb));
        wst[OUT_CH * HID + idx]   = f2bf(ldf(W2r, idx, fb));
    }
    __syncthreads();
    int wave = t >> 6, lane = t & 63;
    int slot = lane >> 4;    // 0..3
    int chunk = lane & 15;   // 0..15
    ush8 wlr[8], wrr[8];
    float bsr[8];
#pragma unroll
    for (int j = 0; j < 8; ++j) {
        int o = slot * 8 + j;
        wlr[j] = *(const ush8*)&wst[o * HID + chunk * 8];
        wrr[j] = *(const ush8*)&wst[OUT_CH * HID + o * HID + chunk * 8];
        bsr[j] = ldf(b2, o, fb);
    }
    int gw = blockIdx.x * 4 + wave;
    int nw = gridDim.x * 4;
    for (int i = gw; i < n_nodes; i += nw) {
        int beg = off[i], end = off[i + 1];
        float acc[8] = {0, 0, 0, 0, 0, 0, 0, 0};
        for (int base = beg; base < end; base += 64) {
            int idxv = csr[min(base + lane, n_edges - 1)];
            int lim = min(64, end - base);
            for (int g = 0; g < lim; g += 16) {
                int k0 = g + slot, k1 = g + 4 + slot, k2 = g + 8 + slot, k3 = g + 12 + slot;
                int s0 = __shfl(idxv, k0), s1 = __shfl(idxv, k1),
                    s2 = __shfl(idxv, k2), s3 = __shfl(idxv, k3);
                bool o0 = k0 < lim, o1 = k1 < lim, o2 = k2 < lim, o3 = k3 < lim;
                // 4 independent row-loads in flight per group
                ush8 v0 = *(const ush8*)(h + (size_t)(o0 ? s0 : i) * HID + chunk * 8);
                ush8 v1 = *(const ush8*)(h + (size_t)(o1 ? s1 : i) * HID + chunk * 8);
                ush8 v2 = *(const ush8*)(h + (size_t)(o2 ? s2 : i) * HID + chunk * 8);
                ush8 v3 = *(const ush8*)(h + (size_t)(o3 ? s3 : i) * HID + chunk * 8);
#pragma unroll
                for (int j = 0; j < 8; ++j)
                    acc[j] += (o0 ? bf2f(v0[j]) : 0.0f) + (o1 ? bf2f(v1[j]) : 0.0f)
                            + (o2 ? bf2f(v2[j]) : 0.0f) + (o3 ? bf2f(v3[j]) : 0.0f);
            }
        }
        // reduce over slot bits (lane bits 4,5)
#pragma unroll
        for (int j = 0; j < 8; ++j) {
            acc[j] += __shfl_xor(acc[j], 16);
            acc[j] += __shfl_xor(acc[j], 32);
        }
        int deg = end - beg;
        float rdeg = 1.0f / (float)(deg > 1 ? deg : 1);
        ush8 svv = *(const ush8*)(h + (size_t)i * HID + chunk * 8);
        float mean[8], sv[8];
#pragma unroll
        for (int j = 0; j < 8; ++j) { mean[j] = acc[j] * rdeg; sv[j] = bf2f(svv[j]); }
        float po[8];
#pragma unroll
        for (int j = 0; j < 8; ++j) {
            float s = 0.0f;
#pragma unroll
            for (int c = 0; c < 8; ++c)
                s += mean[c] * bf2f(wlr[j][c]) + sv[c] * bf2f(wrr[j][c]);
            po[j] = s;
        }
        // reduce over chunk bits (lane bits 0..3)
#pragma unroll
        for (int j = 0; j < 8; ++j) {
            po[j] += __shfl_xor(po[j], 1);
            po[j] += __shfl_xor(po[j], 2);
            po[j] += __shfl_xor(po[j], 4);
            po[j] += __shfl_xor(po[j], 8);
        }
        if (chunk == 0) {
            if (fb) {
                ush8 ov;
#pragma unroll
                for (int j = 0; j < 8; ++j) ov[j] = f2bf(po[j] + bsr[j]);
                *(ush8*)((ush*)out + (size_t)i * OUT_CH + slot * 8) = ov;
            } else {
                float* op = (float*)out + (size_t)i * OUT_CH + slot * 8;
                f4 a0, a1;
#pragma unroll
                for (int j = 0; j < 4; ++j) {
                    a0[j] = po[j] + bsr[j];
                    a1[j] = po[4 + j] + bsr[4 + j];
                }
                *(f4*)op = a0;
                *(f4*)(op + 4) = a1;
            }
        }
    }
}

extern "C" void kernel_launch(void* const* d_in, const int* in_sizes, int n_in,
                              void* d_out, int out_size, void* d_ws, size_t ws_size,
                              hipStream_t stream) {
    const void* x   = d_in[0];
    const int*  ei  = (const int*)d_in[1];
    const void* W1l = d_in[2];
    const void* W1r = d_in[3];
    const void* b1  = d_in[4];
    const void* W2l = d_in[5];
    const void* W2r = d_in[6];
    const void* b2  = d_in[7];

    int n_nodes = in_sizes[0] / IN_CH;
    int n_edges = in_sizes[1] / 2;

    // ws layout (~33 MB): flags | off (N+1) | cursor (N) | csr (E) | h (N*HID bf16)
    char* ws = (char*)d_ws;
    size_t o_off = 256;
    size_t o_cur = (o_off + (size_t)(n_nodes + 1) * 4 + 127) & ~(size_t)127;
    size_t o_csr = (o_cur + (size_t)n_nodes * 4 + 127) & ~(size_t)127;
    size_t o_h   = (o_csr + (size_t)n_edges * 4 + 255) & ~(size_t)255;

    int* flags  = (int*)ws;
    int* deg    = (int*)(ws + o_off);   // becomes offsets after k_scan
    int* cursor = (int*)(ws + o_cur);
    int* csr    = (int*)(ws + o_csr);
    ush* h      = (ush*)(ws + o_h);

    hipMemsetAsync(deg, 0, (size_t)(n_nodes + 1) * 4, stream);

    k_detect<<<1, 256, 0, stream>>>((const unsigned short*)x, ei, flags);
    k_count<<<(n_edges + 255) / 256, 256, 0, stream>>>(ei, n_edges, flags, deg);
    k_scan<<<1, 1024, 0, stream>>>(deg, cursor, n_nodes);
    k_fill<<<(n_edges + 255) / 256, 256, 0, stream>>>(ei, n_edges, flags, cursor, csr);

    k_l1<<<1024, 256, 0, stream>>>(x, deg, csr, W1l, W1r, b1, flags, h, n_nodes, n_edges);
    k_l2<<<1024, 256, 0, stream>>>(h, deg, csr, W2l, W2r, b2, flags, d_out, n_nodes, n_edges);
}

// Round 6
// 596.007 us; speedup vs baseline: 6.5975x; 1.3194x over previous
//
#include <hip/hip_runtime.h>
#include <hip/hip_bf16.h>

typedef __hip_bfloat16 bf16;
typedef unsigned short ush;
typedef __attribute__((ext_vector_type(8))) unsigned short ush8;
typedef __attribute__((ext_vector_type(4))) float f4;

#define IN_CH 32
#define HID 128
#define OUT_CH 32

__device__ __forceinline__ float bf2f(ush u) {
    return __uint_as_float(((unsigned)u) << 16);
}
__device__ __forceinline__ ush f2bf(float f) {
    __hip_bfloat16 b = __float2bfloat16(f);
    return __builtin_bit_cast(ush, b);
}
__device__ __forceinline__ float ldf(const void* __restrict__ p, size_t idx, int isbf16) {
    return isbf16 ? bf2f(((const ush*)p)[idx]) : ((const float*)p)[idx];
}
__device__ __forceinline__ int ld_edge(const int* __restrict__ ei, size_t elem, int wide) {
    return wide ? ei[2 * elem] : ei[elem];
}

// ---------- sniff dtypes: flags[0]=float_is_bf16, flags[1]=edge_is_i64 ----------
__global__ void k_detect(const unsigned short* __restrict__ xraw,
                         const int* __restrict__ ei, int* __restrict__ flags) {
    __shared__ int cnt_exp, any_nz;
    if (threadIdx.x == 0) { cnt_exp = 0; any_nz = 0; }
    __syncthreads();
    int local = 0;
    for (int k = threadIdx.x; k < 4096; k += 256) {
        int e = (xraw[k] >> 7) & 0xFF;
        if (e >= 100 && e <= 140) ++local;
    }
    atomicAdd(&cnt_exp, local);
    for (int k = threadIdx.x; k < 2048; k += 256)
        if (ei[2 * k + 1] != 0) any_nz = 1;   // benign race
    __syncthreads();
    if (threadIdx.x == 0) {
        flags[0] = (cnt_exp > 3500) ? 1 : 0;
        flags[1] = any_nz ? 0 : 1;
    }
}

__global__ void k_count(const int* __restrict__ ei, int n_edges,
                        const int* __restrict__ flags, int* __restrict__ cnt) {
    int e = blockIdx.x * blockDim.x + threadIdx.x;
    if (e >= n_edges) return;
    int w = flags[1];
    atomicAdd(&cnt[ld_edge(ei, (size_t)n_edges + e, w)], 1);
}

// ---------- scan-free CSR region allocation ----------
// Each wave: exclusive prefix of 64 counts + ONE atomicAdd to a global cursor.
// Regions are contiguous per node but arbitrarily ordered across waves — fine,
// since k_l1/k_l2 use start[i] / start[i]+cnt[i], never off[i+1].
__global__ __launch_bounds__(256) void k_alloc(const int* __restrict__ cnt, int n,
                                               int* __restrict__ start,
                                               int* __restrict__ cursor,
                                               int* __restrict__ total) {
    int i = blockIdx.x * blockDim.x + threadIdx.x;
    int lane = threadIdx.x & 63;
    int d = (i < n) ? cnt[i] : 0;
    // Hillis-Steele inclusive prefix within the wave
    int p = d;
#pragma unroll
    for (int off = 1; off < 64; off <<= 1) {
        int v = __shfl_up(p, off);
        if (lane >= off) p += v;
    }
    int wtot = __shfl(p, 63);            // wave total
    int base = 0;
    if (lane == 63) base = atomicAdd(total, wtot);
    base = __shfl(base, 63);
    int s = base + p - d;                // exclusive prefix + wave base
    if (i < n) { start[i] = s; cursor[i] = s; }
}

__global__ void k_fill(const int* __restrict__ ei, int n_edges,
                       const int* __restrict__ flags,
                       int* __restrict__ cursor, int* __restrict__ csr) {
    int e = blockIdx.x * blockDim.x + threadIdx.x;
    if (e >= n_edges) return;
    int w = flags[1];
    int d = ld_edge(ei, (size_t)n_edges + e, w);
    int s = ld_edge(ei, (size_t)e, w);
    int p = atomicAdd(&cursor[d], 1);
    csr[p] = s;
}

// ==== layer 1: h[i] = relu(mean_j x[j] @ W1l^T + x[i] @ W1r^T + b1), 32 -> 128 ====
// wave-per-node; lane = (slot 0..15 = edge slot, chunk 0..3 = 8-channel chunk)
__global__ __launch_bounds__(256) void k_l1(
        const void* __restrict__ x,
        const int* __restrict__ start, const int* __restrict__ cnt,
        const int* __restrict__ csr,
        const void* __restrict__ W1l, const void* __restrict__ W1r,
        const void* __restrict__ b1,
        const int* __restrict__ flags,
        ush* __restrict__ hout, int n_nodes, int n_edges) {
    __shared__ ush wst[2 * HID * IN_CH];   // 16 KB: W1l then W1r, bf16 [o][c]
    int fb = flags[0];
    int t = threadIdx.x;
    for (int idx = t; idx < HID * IN_CH; idx += 256) {
        wst[idx]                 = f2bf(ldf(W1l, idx, fb));
        wst[HID * IN_CH + idx]   = f2bf(ldf(W1r, idx, fb));
    }
    __syncthreads();
    int wave = t >> 6, lane = t & 63;
    int slot = lane >> 2;    // 0..15
    int chunk = lane & 3;    // 0..3
    ush8 wlr[8], wrr[8];
    float bsr[8];
#pragma unroll
    for (int j = 0; j < 8; ++j) {
        int o = slot * 8 + j;
        wlr[j] = *(const ush8*)&wst[o * IN_CH + chunk * 8];
        wrr[j] = *(const ush8*)&wst[HID * IN_CH + o * IN_CH + chunk * 8];
        bsr[j] = ldf(b1, o, fb);
    }
    int gw = blockIdx.x * 4 + wave;
    int nw = gridDim.x * 4;
    for (int i = gw; i < n_nodes; i += nw) {
        int beg = start[i], dg = cnt[i], end = beg + dg;
        float acc[8] = {0, 0, 0, 0, 0, 0, 0, 0};
        if (fb) {
            const ush* xb = (const ush*)x;
            for (int base = beg; base < end; base += 64) {
                int idxv = csr[min(base + lane, n_edges - 1)];
                int lim = min(64, end - base);
                for (int g = 0; g < lim; g += 16) {
                    int k = g + slot;
                    int src = __shfl(idxv, k);
                    bool ok = k < lim;
                    ush8 v = *(const ush8*)(xb + (size_t)(ok ? src : i) * IN_CH + chunk * 8);
#pragma unroll
                    for (int j = 0; j < 8; ++j) acc[j] += ok ? bf2f(v[j]) : 0.0f;
                }
            }
        } else {
            const float* xb = (const float*)x;
            for (int base = beg; base < end; base += 64) {
                int idxv = csr[min(base + lane, n_edges - 1)];
                int lim = min(64, end - base);
                for (int g = 0; g < lim; g += 16) {
                    int k = g + slot;
                    int src = __shfl(idxv, k);
                    bool ok = k < lim;
                    const float* rp = xb + (size_t)(ok ? src : i) * IN_CH + chunk * 8;
                    f4 a0 = *(const f4*)rp;
                    f4 a1 = *(const f4*)(rp + 4);
#pragma unroll
                    for (int j = 0; j < 4; ++j) {
                        acc[j]     += ok ? a0[j] : 0.0f;
                        acc[4 + j] += ok ? a1[j] : 0.0f;
                    }
                }
            }
        }
#pragma unroll
        for (int j = 0; j < 8; ++j) {
            acc[j] += __shfl_xor(acc[j], 4);
            acc[j] += __shfl_xor(acc[j], 8);
            acc[j] += __shfl_xor(acc[j], 16);
            acc[j] += __shfl_xor(acc[j], 32);
        }
        float rdeg = 1.0f / (float)(dg > 1 ? dg : 1);
        float mean[8], sv[8];
        if (fb) {
            ush8 svv = *(const ush8*)((const ush*)x + (size_t)i * IN_CH + chunk * 8);
#pragma unroll
            for (int j = 0; j < 8; ++j) sv[j] = bf2f(svv[j]);
        } else {
            const float* rp = (const float*)x + (size_t)i * IN_CH + chunk * 8;
            f4 a0 = *(const f4*)rp;
            f4 a1 = *(const f4*)(rp + 4);
#pragma unroll
            for (int j = 0; j < 4; ++j) { sv[j] = a0[j]; sv[4 + j] = a1[j]; }
        }
#pragma unroll
        for (int j = 0; j < 8; ++j) mean[j] = acc[j] * rdeg;
        float po[8];
#pragma unroll
        for (int j = 0; j < 8; ++j) {
            float s = 0.0f;
#pragma unroll
            for (int c = 0; c < 8; ++c)
                s += mean[c] * bf2f(wlr[j][c]) + sv[c] * bf2f(wrr[j][c]);
            po[j] = s;
        }
#pragma unroll
        for (int j = 0; j < 8; ++j) {
            po[j] += __shfl_xor(po[j], 1);
            po[j] += __shfl_xor(po[j], 2);
        }
        if (chunk == 0) {
            ush8 ov;
#pragma unroll
            for (int j = 0; j < 8; ++j) {
                float v = po[j] + bsr[j];
                ov[j] = f2bf(v > 0.0f ? v : 0.0f);
            }
            *(ush8*)(hout + (size_t)i * HID + slot * 8) = ov;
        }
    }
}

// ==== layer 2: out[i] = mean_j h[j] @ W2l^T + h[i] @ W2r^T + b2, 128 -> 32 ====
// wave-per-node; lane = (slot 0..3 = edge slot, chunk 0..15 = 8-channel chunk)
__global__ __launch_bounds__(256) void k_l2(
        const ush* __restrict__ h,
        const int* __restrict__ start, const int* __restrict__ cnt,
        const int* __restrict__ csr,
        const void* __restrict__ W2l, const void* __restrict__ W2r,
        const void* __restrict__ b2,
        const int* __restrict__ flags,
        void* __restrict__ out, int n_nodes, int n_edges) {
    __shared__ ush wst[2 * OUT_CH * HID];  // 16 KB
    int fb = flags[0];
    int t = threadIdx.x;
    for (int idx = t; idx < OUT_CH * HID; idx += 256) {
        wst[idx]                  = f2bf(ldf(W2l, idx, fb));
        wst[OUT_CH * HID + idx]   = f2bf(ldf(W2r, idx, fb));
    }
    __syncthreads();
    int wave = t >> 6, lane = t & 63;
    int slot = lane >> 4;    // 0..3
    int chunk = lane & 15;   // 0..15
    ush8 wlr[8], wrr[8];
    float bsr[8];
#pragma unroll
    for (int j = 0; j < 8; ++j) {
        int o = slot * 8 + j;
        wlr[j] = *(const ush8*)&wst[o * HID + chunk * 8];
        wrr[j] = *(const ush8*)&wst[OUT_CH * HID + o * HID + chunk * 8];
        bsr[j] = ldf(b2, o, fb);
    }
    int gw = blockIdx.x * 4 + wave;
    int nw = gridDim.x * 4;
    for (int i = gw; i < n_nodes; i += nw) {
        int beg = start[i], dg = cnt[i], end = beg + dg;
        float acc[8] = {0, 0, 0, 0, 0, 0, 0, 0};
        for (int base = beg; base < end; base += 64) {
            int idxv = csr[min(base + lane, n_edges - 1)];
            int lim = min(64, end - base);
            for (int g = 0; g < lim; g += 16) {
                int k0 = g + slot, k1 = g + 4 + slot, k2 = g + 8 + slot, k3 = g + 12 + slot;
                int s0 = __shfl(idxv, k0), s1 = __shfl(idxv, k1),
                    s2 = __shfl(idxv, k2), s3 = __shfl(idxv, k3);
                bool o0 = k0 < lim, o1 = k1 < lim, o2 = k2 < lim, o3 = k3 < lim;
                ush8 v0 = *(const ush8*)(h + (size_t)(o0 ? s0 : i) * HID + chunk * 8);
                ush8 v1 = *(const ush8*)(h + (size_t)(o1 ? s1 : i) * HID + chunk * 8);
                ush8 v2 = *(const ush8*)(h + (size_t)(o2 ? s2 : i) * HID + chunk * 8);
                ush8 v3 = *(const ush8*)(h + (size_t)(o3 ? s3 : i) * HID + chunk * 8);
#pragma unroll
                for (int j = 0; j < 8; ++j)
                    acc[j] += (o0 ? bf2f(v0[j]) : 0.0f) + (o1 ? bf2f(v1[j]) : 0.0f)
                            + (o2 ? bf2f(v2[j]) : 0.0f) + (o3 ? bf2f(v3[j]) : 0.0f);
            }
        }
#pragma unroll
        for (int j = 0; j < 8; ++j) {
            acc[j] += __shfl_xor(acc[j], 16);
            acc[j] += __shfl_xor(acc[j], 32);
        }
        float rdeg = 1.0f / (float)(dg > 1 ? dg : 1);
        ush8 svv = *(const ush8*)(h + (size_t)i * HID + chunk * 8);
        float mean[8], sv[8];
#pragma unroll
        for (int j = 0; j < 8; ++j) { mean[j] = acc[j] * rdeg; sv[j] = bf2f(svv[j]); }
        float po[8];
#pragma unroll
        for (int j = 0; j < 8; ++j) {
            float s = 0.0f;
#pragma unroll
            for (int c = 0; c < 8; ++c)
                s += mean[c] * bf2f(wlr[j][c]) + sv[c] * bf2f(wrr[j][c]);
            po[j] = s;
        }
#pragma unroll
        for (int j = 0; j < 8; ++j) {
            po[j] += __shfl_xor(po[j], 1);
            po[j] += __shfl_xor(po[j], 2);
            po[j] += __shfl_xor(po[j], 4);
            po[j] += __shfl_xor(po[j], 8);
        }
        if (chunk == 0) {
            if (fb) {
                ush8 ov;
#pragma unroll
                for (int j = 0; j < 8; ++j) ov[j] = f2bf(po[j] + bsr[j]);
                *(ush8*)((ush*)out + (size_t)i * OUT_CH + slot * 8) = ov;
            } else {
                float* op = (float*)out + (size_t)i * OUT_CH + slot * 8;
                f4 a0, a1;
#pragma unroll
                for (int j = 0; j < 4; ++j) {
                    a0[j] = po[j] + bsr[j];
                    a1[j] = po[4 + j] + bsr[4 + j];
                }
                *(f4*)op = a0;
                *(f4*)(op + 4) = a1;
            }
        }
    }
}

extern "C" void kernel_launch(void* const* d_in, const int* in_sizes, int n_in,
                              void* d_out, int out_size, void* d_ws, size_t ws_size,
                              hipStream_t stream) {
    const void* x   = d_in[0];
    const int*  ei  = (const int*)d_in[1];
    const void* W1l = d_in[2];
    const void* W1r = d_in[3];
    const void* b1  = d_in[4];
    const void* W2l = d_in[5];
    const void* W2r = d_in[6];
    const void* b2  = d_in[7];

    int n_nodes = in_sizes[0] / IN_CH;
    int n_edges = in_sizes[1] / 2;

    // ws layout (~33.5 MB):
    //   [0,256)   flags (2 ints) + total counter (at +128)
    //   cnt (N) | start (N) | cursor (N) | csr (E) | h (N*HID bf16)
    char* ws = (char*)d_ws;
    size_t o_cnt   = 256;
    size_t o_start = (o_cnt   + (size_t)n_nodes * 4 + 127) & ~(size_t)127;
    size_t o_cur   = (o_start + (size_t)n_nodes * 4 + 127) & ~(size_t)127;
    size_t o_csr   = (o_cur   + (size_t)n_nodes * 4 + 127) & ~(size_t)127;
    size_t o_h     = (o_csr   + (size_t)n_edges * 4 + 255) & ~(size_t)255;

    int* flags  = (int*)ws;
    int* total  = (int*)(ws + 128);
    int* cnt    = (int*)(ws + o_cnt);
    int* start  = (int*)(ws + o_start);
    int* cursor = (int*)(ws + o_cur);
    int* csr    = (int*)(ws + o_csr);
    ush* h      = (ush*)(ws + o_h);

    hipMemsetAsync(ws, 0, 256, stream);                          // flags + total
    hipMemsetAsync(cnt, 0, (size_t)n_nodes * 4, stream);

    k_detect<<<1, 256, 0, stream>>>((const unsigned short*)x, ei, flags);
    k_count<<<(n_edges + 255) / 256, 256, 0, stream>>>(ei, n_edges, flags, cnt);
    k_alloc<<<(n_nodes + 255) / 256, 256, 0, stream>>>(cnt, n_nodes, start, cursor, total);
    k_fill<<<(n_edges + 255) / 256, 256, 0, stream>>>(ei, n_edges, flags, cursor, csr);

    k_l1<<<1024, 256, 0, stream>>>(x, start, cnt, csr, W1l, W1r, b1, flags, h, n_nodes, n_edges);
    k_l2<<<1024, 256, 0, stream>>>(h, start, cnt, csr, W2l, W2r, b2, flags, d_out, n_nodes, n_edges);
}

// Round 7
// 592.083 us; speedup vs baseline: 6.6412x; 1.0066x over previous
//
#include <hip/hip_runtime.h>
#include <hip/hip_bf16.h>

typedef __hip_bfloat16 bf16;
typedef unsigned short ush;
typedef __attribute__((ext_vector_type(8))) unsigned short ush8;
typedef __attribute__((ext_vector_type(4))) float f4;

#define IN_CH 32
#define HID 128
#define OUT_CH 32

__device__ __forceinline__ float bf2f(ush u) {
    return __uint_as_float(((unsigned)u) << 16);
}
__device__ __forceinline__ ush f2bf(float f) {
    __hip_bfloat16 b = __float2bfloat16(f);
    return __builtin_bit_cast(ush, b);
}
__device__ __forceinline__ float ldf(const void* __restrict__ p, size_t idx, int isbf16) {
    return isbf16 ? bf2f(((const ush*)p)[idx]) : ((const float*)p)[idx];
}
__device__ __forceinline__ int ld_edge(const int* __restrict__ ei, size_t elem, int wide) {
    return wide ? ei[2 * elem] : ei[elem];
}

// ---------- sniff dtypes: flags[0]=float_is_bf16, flags[1]=edge_is_i64 ----------
__global__ void k_detect(const unsigned short* __restrict__ xraw,
                         const int* __restrict__ ei, int* __restrict__ flags) {
    __shared__ int cnt_exp, any_nz;
    if (threadIdx.x == 0) { cnt_exp = 0; any_nz = 0; }
    __syncthreads();
    int local = 0;
    for (int k = threadIdx.x; k < 4096; k += 256) {
        int e = (xraw[k] >> 7) & 0xFF;
        if (e >= 100 && e <= 140) ++local;
    }
    atomicAdd(&cnt_exp, local);
    for (int k = threadIdx.x; k < 2048; k += 256)
        if (ei[2 * k + 1] != 0) any_nz = 1;   // benign race
    __syncthreads();
    if (threadIdx.x == 0) {
        flags[0] = (cnt_exp > 3500) ? 1 : 0;
        flags[1] = any_nz ? 0 : 1;
    }
}

__global__ void k_count(const int* __restrict__ ei, int n_edges,
                        const int* __restrict__ flags, int* __restrict__ cnt) {
    int e = blockIdx.x * blockDim.x + threadIdx.x;
    if (e >= n_edges) return;
    int w = flags[1];
    atomicAdd(&cnt[ld_edge(ei, (size_t)n_edges + e, w)], 1);
}

// ---------- scan-free CSR region allocation (one atomic per wave) ----------
__global__ __launch_bounds__(256) void k_alloc(const int* __restrict__ cnt, int n,
                                               int* __restrict__ start,
                                               int* __restrict__ cursor,
                                               int* __restrict__ total) {
    int i = blockIdx.x * blockDim.x + threadIdx.x;
    int lane = threadIdx.x & 63;
    int d = (i < n) ? cnt[i] : 0;
    int p = d;
#pragma unroll
    for (int off = 1; off < 64; off <<= 1) {
        int v = __shfl_up(p, off);
        if (lane >= off) p += v;
    }
    int wtot = __shfl(p, 63);
    int base = 0;
    if (lane == 63) base = atomicAdd(total, wtot);
    base = __shfl(base, 63);
    int s = base + p - d;
    if (i < n) { start[i] = s; cursor[i] = s; }
}

__global__ void k_fill(const int* __restrict__ ei, int n_edges,
                       const int* __restrict__ flags,
                       int* __restrict__ cursor, int* __restrict__ csr) {
    int e = blockIdx.x * blockDim.x + threadIdx.x;
    if (e >= n_edges) return;
    int w = flags[1];
    int d = ld_edge(ei, (size_t)n_edges + e, w);
    int s = ld_edge(ei, (size_t)e, w);
    int p = atomicAdd(&cursor[d], 1);
    csr[p] = s;
}

// ==== layer 1: h[i] = relu(mean_j x[j] @ W1l^T + x[i] @ W1r^T + b1), 32 -> 128 ====
// wave-per-node; lane = (slot 0..15 = edge slot, chunk 0..3 = 8-channel chunk)
__global__ __launch_bounds__(256) void k_l1(
        const void* __restrict__ x,
        const int* __restrict__ start, const int* __restrict__ cnt,
        const int* __restrict__ csr,
        const void* __restrict__ W1l, const void* __restrict__ W1r,
        const void* __restrict__ b1,
        const int* __restrict__ flags,
        ush* __restrict__ hout, int n_nodes, int n_edges) {
    __shared__ ush wst[2 * HID * IN_CH];   // 16 KB: W1l then W1r, bf16 [o][c]
    int fb = flags[0];
    int t = threadIdx.x;
    for (int idx = t; idx < HID * IN_CH; idx += 256) {
        wst[idx]                 = f2bf(ldf(W1l, idx, fb));
        wst[HID * IN_CH + idx]   = f2bf(ldf(W1r, idx, fb));
    }
    __syncthreads();
    int wave = t >> 6, lane = t & 63;
    int slot = lane >> 2;    // 0..15
    int chunk = lane & 3;    // 0..3
    ush8 wlr[8], wrr[8];
    float bsr[8];
#pragma unroll
    for (int j = 0; j < 8; ++j) {
        int o = slot * 8 + j;
        wlr[j] = *(const ush8*)&wst[o * IN_CH + chunk * 8];
        wrr[j] = *(const ush8*)&wst[HID * IN_CH + o * IN_CH + chunk * 8];
        bsr[j] = ldf(b1, o, fb);
    }
    int gw = blockIdx.x * 4 + wave;
    int nw = gridDim.x * 4;
    for (int i = gw; i < n_nodes; i += nw) {
        int beg = start[i], dg = cnt[i], end = beg + dg;
        float acc[8] = {0, 0, 0, 0, 0, 0, 0, 0};
        if (fb) {
            const ush* xb = (const ush*)x;
            for (int base = beg; base < end; base += 64) {
                int idxv = csr[min(base + lane, n_edges - 1)];
                int lim = min(64, end - base);
                for (int g = 0; g < lim; g += 16) {
                    int k = g + slot;
                    int src = __shfl(idxv, k);
                    bool ok = k < lim;
                    ush8 v = *(const ush8*)(xb + (size_t)(ok ? src : i) * IN_CH + chunk * 8);
#pragma unroll
                    for (int j = 0; j < 8; ++j) acc[j] += ok ? bf2f(v[j]) : 0.0f;
                }
            }
        } else {
            const float* xb = (const float*)x;
            for (int base = beg; base < end; base += 64) {
                int idxv = csr[min(base + lane, n_edges - 1)];
                int lim = min(64, end - base);
                for (int g = 0; g < lim; g += 16) {
                    int k = g + slot;
                    int src = __shfl(idxv, k);
                    bool ok = k < lim;
                    const float* rp = xb + (size_t)(ok ? src : i) * IN_CH + chunk * 8;
                    f4 a0 = *(const f4*)rp;
                    f4 a1 = *(const f4*)(rp + 4);
#pragma unroll
                    for (int j = 0; j < 4; ++j) {
                        acc[j]     += ok ? a0[j] : 0.0f;
                        acc[4 + j] += ok ? a1[j] : 0.0f;
                    }
                }
            }
        }
#pragma unroll
        for (int j = 0; j < 8; ++j) {
            acc[j] += __shfl_xor(acc[j], 4);
            acc[j] += __shfl_xor(acc[j], 8);
            acc[j] += __shfl_xor(acc[j], 16);
            acc[j] += __shfl_xor(acc[j], 32);
        }
        float rdeg = 1.0f / (float)(dg > 1 ? dg : 1);
        float mean[8], sv[8];
        if (fb) {
            ush8 svv = *(const ush8*)((const ush*)x + (size_t)i * IN_CH + chunk * 8);
#pragma unroll
            for (int j = 0; j < 8; ++j) sv[j] = bf2f(svv[j]);
        } else {
            const float* rp = (const float*)x + (size_t)i * IN_CH + chunk * 8;
            f4 a0 = *(const f4*)rp;
            f4 a1 = *(const f4*)(rp + 4);
#pragma unroll
            for (int j = 0; j < 4; ++j) { sv[j] = a0[j]; sv[4 + j] = a1[j]; }
        }
#pragma unroll
        for (int j = 0; j < 8; ++j) mean[j] = acc[j] * rdeg;
        float po[8];
#pragma unroll
        for (int j = 0; j < 8; ++j) {
            float s = 0.0f;
#pragma unroll
            for (int c = 0; c < 8; ++c)
                s += mean[c] * bf2f(wlr[j][c]) + sv[c] * bf2f(wrr[j][c]);
            po[j] = s;
        }
#pragma unroll
        for (int j = 0; j < 8; ++j) {
            po[j] += __shfl_xor(po[j], 1);
            po[j] += __shfl_xor(po[j], 2);
        }
        if (chunk == 0) {
            ush8 ov;
#pragma unroll
            for (int j = 0; j < 8; ++j) {
                float v = po[j] + bsr[j];
                ov[j] = f2bf(v > 0.0f ? v : 0.0f);
            }
            *(ush8*)(hout + (size_t)i * HID + slot * 8) = ov;
        }
    }
}

// ==== g = h @ W2l^T (bf16), s = h @ W2r^T + b2 (bf16) — dense, per node ====
// wave-per-node; lane = (slot 0..3 = 8-output group, chunk 0..15 = 8-channel chunk)
__global__ __launch_bounds__(256) void k_g(
        const ush* __restrict__ h,
        const void* __restrict__ W2l, const void* __restrict__ W2r,
        const void* __restrict__ b2,
        const int* __restrict__ flags,
        ush* __restrict__ g, ush* __restrict__ s, int n_nodes) {
    __shared__ ush wst[2 * OUT_CH * HID];  // 16 KB
    int fb = flags[0];
    int t = threadIdx.x;
    for (int idx = t; idx < OUT_CH * HID; idx += 256) {
        wst[idx]                  = f2bf(ldf(W2l, idx, fb));
        wst[OUT_CH * HID + idx]   = f2bf(ldf(W2r, idx, fb));
    }
    __syncthreads();
    int wave = t >> 6, lane = t & 63;
    int slot = lane >> 4;    // 0..3
    int chunk = lane & 15;   // 0..15
    ush8 wlr[8], wrr[8];
    float bsr[8];
#pragma unroll
    for (int j = 0; j < 8; ++j) {
        int o = slot * 8 + j;
        wlr[j] = *(const ush8*)&wst[o * HID + chunk * 8];
        wrr[j] = *(const ush8*)&wst[OUT_CH * HID + o * HID + chunk * 8];
        bsr[j] = ldf(b2, o, fb);
    }
    int gw = blockIdx.x * 4 + wave;
    int nw = gridDim.x * 4;
    for (int i = gw; i < n_nodes; i += nw) {
        ush8 hv = *(const ush8*)(h + (size_t)i * HID + chunk * 8);
        float sv[8];
#pragma unroll
        for (int j = 0; j < 8; ++j) sv[j] = bf2f(hv[j]);
        float pg[8], ps[8];
#pragma unroll
        for (int j = 0; j < 8; ++j) {
            float a = 0.0f, b = 0.0f;
#pragma unroll
            for (int c = 0; c < 8; ++c) {
                a += sv[c] * bf2f(wlr[j][c]);
                b += sv[c] * bf2f(wrr[j][c]);
            }
            pg[j] = a; ps[j] = b;
        }
#pragma unroll
        for (int j = 0; j < 8; ++j) {
            pg[j] += __shfl_xor(pg[j], 1);
            pg[j] += __shfl_xor(pg[j], 2);
            pg[j] += __shfl_xor(pg[j], 4);
            pg[j] += __shfl_xor(pg[j], 8);
            ps[j] += __shfl_xor(ps[j], 1);
            ps[j] += __shfl_xor(ps[j], 2);
            ps[j] += __shfl_xor(ps[j], 4);
            ps[j] += __shfl_xor(ps[j], 8);
        }
        if (chunk == 0) {
            ush8 go, so;
#pragma unroll
            for (int j = 0; j < 8; ++j) {
                go[j] = f2bf(pg[j]);
                so[j] = f2bf(ps[j] + bsr[j]);
            }
            *(ush8*)(g + (size_t)i * OUT_CH + slot * 8) = go;
            *(ush8*)(s + (size_t)i * OUT_CH + slot * 8) = so;
        }
    }
}

// ==== out[i] = mean_j g[j] + s[i] — pure 64B-row gather ====
// wave-per-node; lane = (slot 0..15 = edge slot, chunk 0..3 = 8-channel chunk)
__global__ __launch_bounds__(256) void k_l2g(
        const ush* __restrict__ g, const ush* __restrict__ s,
        const int* __restrict__ start, const int* __restrict__ cnt,
        const int* __restrict__ csr,
        const int* __restrict__ flags,
        void* __restrict__ out, int n_nodes, int n_edges) {
    int fb = flags[0];
    int t = threadIdx.x;
    int wave = t >> 6, lane = t & 63;
    int slot = lane >> 2;    // 0..15
    int chunk = lane & 3;    // 0..3
    int gw = blockIdx.x * 4 + wave;
    int nw = gridDim.x * 4;
    for (int i = gw; i < n_nodes; i += nw) {
        int beg = start[i], dg = cnt[i], end = beg + dg;
        float acc[8] = {0, 0, 0, 0, 0, 0, 0, 0};
        for (int base = beg; base < end; base += 64) {
            int idxv = csr[min(base + lane, n_edges - 1)];
            int lim = min(64, end - base);
            for (int gg = 0; gg < lim; gg += 16) {
                int k = gg + slot;
                int src = __shfl(idxv, k);
                bool ok = k < lim;
                ush8 v = *(const ush8*)(g + (size_t)(ok ? src : i) * OUT_CH + chunk * 8);
#pragma unroll
                for (int j = 0; j < 8; ++j) acc[j] += ok ? bf2f(v[j]) : 0.0f;
            }
        }
#pragma unroll
        for (int j = 0; j < 8; ++j) {
            acc[j] += __shfl_xor(acc[j], 4);
            acc[j] += __shfl_xor(acc[j], 8);
            acc[j] += __shfl_xor(acc[j], 16);
            acc[j] += __shfl_xor(acc[j], 32);
        }
        if (slot == 0) {   // lanes 0..3 hold chunk 0..3
            float rdeg = 1.0f / (float)(dg > 1 ? dg : 1);
            ush8 selfv = *(const ush8*)(s + (size_t)i * OUT_CH + chunk * 8);
            if (fb) {
                ush8 ov;
#pragma unroll
                for (int j = 0; j < 8; ++j)
                    ov[j] = f2bf(acc[j] * rdeg + bf2f(selfv[j]));
                *(ush8*)((ush*)out + (size_t)i * OUT_CH + chunk * 8) = ov;
            } else {
                float* op = (float*)out + (size_t)i * OUT_CH + chunk * 8;
                f4 a0, a1;
#pragma unroll
                for (int j = 0; j < 4; ++j) {
                    a0[j] = acc[j] * rdeg + bf2f(selfv[j]);
                    a1[j] = acc[4 + j] * rdeg + bf2f(selfv[4 + j]);
                }
                *(f4*)op = a0;
                *(f4*)(op + 4) = a1;
            }
        }
    }
}

extern "C" void kernel_launch(void* const* d_in, const int* in_sizes, int n_in,
                              void* d_out, int out_size, void* d_ws, size_t ws_size,
                              hipStream_t stream) {
    const void* x   = d_in[0];
    const int*  ei  = (const int*)d_in[1];
    const void* W1l = d_in[2];
    const void* W1r = d_in[3];
    const void* b1  = d_in[4];
    const void* W2l = d_in[5];
    const void* W2r = d_in[6];
    const void* b2  = d_in[7];

    int n_nodes = in_sizes[0] / IN_CH;
    int n_edges = in_sizes[1] / 2;

    // ws layout (~46 MB):
    //   [0,256)   flags (2 ints) + total counter (at +128)
    //   cnt (N) | start (N) | cursor (N) | csr (E) | h (N*HID bf16)
    //   | g (N*OUT bf16) | s (N*OUT bf16)
    char* ws = (char*)d_ws;
    size_t o_cnt   = 256;
    size_t o_start = (o_cnt   + (size_t)n_nodes * 4 + 127) & ~(size_t)127;
    size_t o_cur   = (o_start + (size_t)n_nodes * 4 + 127) & ~(size_t)127;
    size_t o_csr   = (o_cur   + (size_t)n_nodes * 4 + 127) & ~(size_t)127;
    size_t o_h     = (o_csr   + (size_t)n_edges * 4 + 255) & ~(size_t)255;
    size_t o_g     = (o_h     + (size_t)n_nodes * HID * 2 + 255) & ~(size_t)255;
    size_t o_s     = (o_g     + (size_t)n_nodes * OUT_CH * 2 + 255) & ~(size_t)255;

    int* flags  = (int*)ws;
    int* total  = (int*)(ws + 128);
    int* cnt    = (int*)(ws + o_cnt);
    int* start  = (int*)(ws + o_start);
    int* cursor = (int*)(ws + o_cur);
    int* csr    = (int*)(ws + o_csr);
    ush* h      = (ush*)(ws + o_h);
    ush* g      = (ush*)(ws + o_g);
    ush* s      = (ush*)(ws + o_s);

    hipMemsetAsync(ws, 0, 256, stream);                          // flags + total
    hipMemsetAsync(cnt, 0, (size_t)n_nodes * 4, stream);

    k_detect<<<1, 256, 0, stream>>>((const unsigned short*)x, ei, flags);
    k_count<<<(n_edges + 255) / 256, 256, 0, stream>>>(ei, n_edges, flags, cnt);
    k_alloc<<<(n_nodes + 255) / 256, 256, 0, stream>>>(cnt, n_nodes, start, cursor, total);
    k_fill<<<(n_edges + 255) / 256, 256, 0, stream>>>(ei, n_edges, flags, cursor, csr);

    k_l1<<<1024, 256, 0, stream>>>(x, start, cnt, csr, W1l, W1r, b1, flags, h, n_nodes, n_edges);
    k_g<<<512, 256, 0, stream>>>(h, W2l, W2r, b2, flags, g, s, n_nodes);
    k_l2g<<<1024, 256, 0, stream>>>(g, s, start, cnt, csr, flags, d_out, n_nodes, n_edges);
}